// Round 1
// baseline (495.309 us; speedup 1.0000x reference)
//
#include <hip/hip_runtime.h>
#include <hip/hip_bf16.h>
#include <stdint.h>

#define TOKENS 4096
#define IN_F   4096
#define OUT_F  11008
#define PACKS  512          // IN_F/8
#define GCOUNT 32           // IN_F/128

#define BM 128
#define BN 128
#define BK 64

typedef __attribute__((ext_vector_type(8))) short bf16x8;
typedef __attribute__((ext_vector_type(4))) float f32x4;

static __device__ __forceinline__ short f2bf(float f) {
    union { __hip_bfloat16 h; short s; } u;
    u.h = __float2bfloat16(f);
    return u.s;
}

// ---------------- pre-pass: x fp32 -> bf16 ----------------
__global__ __launch_bounds__(256) void cvt_x_kernel(const float* __restrict__ x,
                                                    short* __restrict__ xb) {
    int i = blockIdx.x * 256 + threadIdx.x;          // one chunk of 8 floats
    const float4* s = (const float4*)x + (size_t)i * 2;
    float4 a = s[0], b = s[1];
    bf16x8 v;
    v[0] = f2bf(a.x); v[1] = f2bf(a.y); v[2] = f2bf(a.z); v[3] = f2bf(a.w);
    v[4] = f2bf(b.x); v[5] = f2bf(b.y); v[6] = f2bf(b.z); v[7] = f2bf(b.w);
    ((bf16x8*)xb)[i] = v;
}

// ---------------- pre-pass: dequant W -> bf16 [OUT_F][IN_F] ----------------
__global__ __launch_bounds__(256) void dequant_w_kernel(const int* __restrict__ qw,
                                                        const int* __restrict__ qz,
                                                        const float* __restrict__ sc,
                                                        short* __restrict__ wb) {
    int i = blockIdx.x * 256 + threadIdx.x;          // pack index: o*512 + p
    int o = i >> 9;
    int p = i & 511;
    int g = p >> 4;                                   // k = 8p..8p+7, group = p/16
    float z = (float)qz[(size_t)g * OUT_F + o];
    float s = sc[(size_t)g * OUT_F + o];
    float zs = z * s;
    int w = qw[i];
    bf16x8 v;
#pragma unroll
    for (int j = 0; j < 8; ++j) {
        float q = (float)((w >> (4 * j)) & 15);
        v[j] = f2bf(q * s - zs);                      // (q - z) * s
    }
    ((bf16x8*)wb)[i] = v;                             // byte offset i*16 == (o*4096+8p)*2
}

// ---------------- shared MFMA inner tile ----------------
__device__ __forceinline__ void mfma_tile(const short* As, const short* Bs,
                                          f32x4 acc[4][4], int lane, int wm, int wn) {
#pragma unroll
    for (int kk = 0; kk < BK; kk += 32) {
        const int kb = kk + (lane >> 4) * 8;
        bf16x8 af[4], bfr[4];
#pragma unroll
        for (int m = 0; m < 4; ++m) {
            int r = wm * 64 + m * 16 + (lane & 15);
            af[m] = *(const bf16x8*)(As + r * BK + kb);
        }
#pragma unroll
        for (int n = 0; n < 4; ++n) {
            int c = wn * 64 + n * 16 + (lane & 15);
            bfr[n] = *(const bf16x8*)(Bs + c * BK + kb);
        }
#pragma unroll
        for (int m = 0; m < 4; ++m)
#pragma unroll
            for (int n = 0; n < 4; ++n)
                acc[m][n] = __builtin_amdgcn_mfma_f32_16x16x32_bf16(af[m], bfr[n],
                                                                    acc[m][n], 0, 0, 0);
    }
}

__device__ __forceinline__ void write_c(float* __restrict__ C, f32x4 acc[4][4],
                                        int row0, int col0, int lane, int wm, int wn) {
#pragma unroll
    for (int m = 0; m < 4; ++m)
#pragma unroll
        for (int n = 0; n < 4; ++n) {
            int r = row0 + wm * 64 + m * 16 + ((lane >> 4) << 2);
            int c = col0 + wn * 64 + n * 16 + (lane & 15);
#pragma unroll
            for (int j = 0; j < 4; ++j)
                C[(size_t)(r + j) * OUT_F + c] = acc[m][n][j];
        }
}

// ---------------- main GEMM, pre-dequantized bf16 path ----------------
__global__ __launch_bounds__(256) void gemm_pre_kernel(const short* __restrict__ A,
                                                       const short* __restrict__ B,
                                                       float* __restrict__ C) {
    const int nbn = OUT_F / BN;                 // 86
    const int nwg = (TOKENS / BM) * nbn;        // 2752, divisible by 8
    const int cpx = nwg >> 3;
    int bid = blockIdx.x;
    int swz = (bid & 7) * cpx + (bid >> 3);     // XCD-contiguous
    int bm = swz / nbn, bn = swz % nbn;
    const int row0 = bm * BM, col0 = bn * BN;

    __shared__ short As[BM * BK];
    __shared__ short Bs[BN * BK];

    const int tid = threadIdx.x;
    const int lane = tid & 63;
    const int wid = tid >> 6;
    const int wm = wid >> 1, wn = wid & 1;

    f32x4 acc[4][4] = {};

    for (int kt = 0; kt < IN_F; kt += BK) {
        // stage A and B via global_load_lds (16B/lane): 16 chunks of 1KB each,
        // chunk c = rows c*8..c*8+7 (row = 64 bf16 = 128B). LDS base wave-uniform.
#pragma unroll
        for (int c = wid; c < 16; c += 4) {
            const short* ga = A + (size_t)(row0 + c * 8 + (lane >> 3)) * IN_F + kt + (lane & 7) * 8;
            __builtin_amdgcn_global_load_lds((const __attribute__((address_space(1))) void*)ga,
                                             (__attribute__((address_space(3))) void*)(As + c * 512),
                                             16, 0, 0);
        }
#pragma unroll
        for (int c = wid; c < 16; c += 4) {
            const short* gb = B + (size_t)(col0 + c * 8 + (lane >> 3)) * IN_F + kt + (lane & 7) * 8;
            __builtin_amdgcn_global_load_lds((const __attribute__((address_space(1))) void*)gb,
                                             (__attribute__((address_space(3))) void*)(Bs + c * 512),
                                             16, 0, 0);
        }
        __syncthreads();                        // drains vmcnt before barrier
        mfma_tile(As, Bs, acc, lane, wm, wn);
        __syncthreads();                        // compute done before next overwrite
    }
    write_c(C, acc, row0, col0, lane, wm, wn);
}

// ---------------- fallback: fused dequant GEMM (reg-staged) ----------------
__global__ __launch_bounds__(256) void gemm_fused_kernel(const float* __restrict__ x,
                                                         const int* __restrict__ qw,
                                                         const int* __restrict__ qz,
                                                         const float* __restrict__ sc,
                                                         float* __restrict__ C) {
    const int nbn = OUT_F / BN;
    const int nwg = (TOKENS / BM) * nbn;
    const int cpx = nwg >> 3;
    int bid = blockIdx.x;
    int swz = (bid & 7) * cpx + (bid >> 3);
    int bm = swz / nbn, bn = swz % nbn;
    const int row0 = bm * BM, col0 = bn * BN;

    __shared__ short As[BM * BK];
    __shared__ short Bs[BN * BK];

    const int tid = threadIdx.x;
    const int lane = tid & 63;
    const int wid = tid >> 6;
    const int wm = wid >> 1, wn = wid & 1;

    f32x4 acc[4][4] = {};

    for (int kt = 0; kt < IN_F; kt += BK) {
        // --- stage A: fp32 -> bf16 ---
#pragma unroll
        for (int i = 0; i < 4; ++i) {
            int idx = i * 256 + tid;            // 1024 chunks of 8 floats
            int r = idx >> 3, kc = (idx & 7) * 8;
            const float4* src = (const float4*)(x + (size_t)(row0 + r) * IN_F + kt + kc);
            float4 a = src[0], b = src[1];
            bf16x8 v;
            v[0] = f2bf(a.x); v[1] = f2bf(a.y); v[2] = f2bf(a.z); v[3] = f2bf(a.w);
            v[4] = f2bf(b.x); v[5] = f2bf(b.y); v[6] = f2bf(b.z); v[7] = f2bf(b.w);
            *(bf16x8*)(As + r * BK + kc) = v;
        }
        // --- stage B: int4 dequant -> bf16 ---
        {
            int ol = tid >> 1;                  // column within tile
            int kc = (tid & 1) * 32;
            const int4* src = (const int4*)(qw + (size_t)(col0 + ol) * PACKS + ((kt + kc) >> 3));
            int4 w4 = *src;
            int g = kt >> 7;                    // all k in [kt, kt+64) share one group
            float z = (float)qz[(size_t)g * OUT_F + col0 + ol];
            float s = sc[(size_t)g * OUT_F + col0 + ol];
            float zs = z * s;
            const int* wp = (const int*)&w4;
#pragma unroll
            for (int c2 = 0; c2 < 4; ++c2) {
                int w32 = wp[c2];
                bf16x8 v;
#pragma unroll
                for (int j = 0; j < 8; ++j)
                    v[j] = f2bf((float)((w32 >> (4 * j)) & 15) * s - zs);
                *(bf16x8*)(Bs + ol * BK + kc + c2 * 8) = v;
            }
        }
        __syncthreads();
        mfma_tile(As, Bs, acc, lane, wm, wn);
        __syncthreads();
    }
    write_c(C, acc, row0, col0, lane, wm, wn);
}

extern "C" void kernel_launch(void* const* d_in, const int* in_sizes, int n_in,
                              void* d_out, int out_size, void* d_ws, size_t ws_size,
                              hipStream_t stream) {
    const float* x = (const float*)d_in[0];
    const int* qw = (const int*)d_in[1];
    const int* qz = (const int*)d_in[2];
    const float* sc = (const float*)d_in[3];
    float* out = (float*)d_out;

    const size_t xb_elems = (size_t)TOKENS * IN_F;            // bf16
    const size_t wb_elems = (size_t)OUT_F * IN_F;             // bf16
    const size_t need = (xb_elems + wb_elems) * sizeof(short); // ~124 MB
    const int ngemm = (TOKENS / BM) * (OUT_F / BN);           // 2752

    if (ws_size >= need) {
        short* xb = (short*)d_ws;
        short* wb = xb + xb_elems;
        cvt_x_kernel<<<(TOKENS * IN_F / 8) / 256, 256, 0, stream>>>(x, xb);
        dequant_w_kernel<<<(OUT_F * PACKS) / 256, 256, 0, stream>>>(qw, qz, sc, wb);
        gemm_pre_kernel<<<ngemm, 256, 0, stream>>>(xb, wb, out);
    } else {
        gemm_fused_kernel<<<ngemm, 256, 0, stream>>>(x, qw, qz, sc, out);
    }
}

// Round 2
// 425.032 us; speedup vs baseline: 1.1653x; 1.1653x over previous
//
#include <hip/hip_runtime.h>
#include <hip/hip_bf16.h>
#include <stdint.h>

#define TOKENS 4096
#define IN_F   4096
#define OUT_F  11008
#define PACKS  512          // IN_F/8
#define GCOUNT 32           // IN_F/128

#define BM 256
#define BN 256
#define BK 64
#define NKT (IN_F / BK)     // 64

typedef __attribute__((ext_vector_type(8))) short bf16x8;
typedef __attribute__((ext_vector_type(4))) float f32x4;

#define AS1 __attribute__((address_space(1)))
#define AS3 __attribute__((address_space(3)))

static __device__ __forceinline__ short f2bf(float f) {
    union { __hip_bfloat16 h; short s; } u;
    u.h = __float2bfloat16(f);
    return u.s;
}

// ---------------- pre-pass: x fp32 -> bf16 ----------------
__global__ __launch_bounds__(256) void cvt_x_kernel(const float* __restrict__ x,
                                                    short* __restrict__ xb) {
    int i = blockIdx.x * 256 + threadIdx.x;
    const float4* s = (const float4*)x + (size_t)i * 2;
    float4 a = s[0], b = s[1];
    bf16x8 v;
    v[0] = f2bf(a.x); v[1] = f2bf(a.y); v[2] = f2bf(a.z); v[3] = f2bf(a.w);
    v[4] = f2bf(b.x); v[5] = f2bf(b.y); v[6] = f2bf(b.z); v[7] = f2bf(b.w);
    ((bf16x8*)xb)[i] = v;
}

// ---------------- pre-pass: dequant W -> bf16 [OUT_F][IN_F] ----------------
__global__ __launch_bounds__(256) void dequant_w_kernel(const int* __restrict__ qw,
                                                        const int* __restrict__ qz,
                                                        const float* __restrict__ sc,
                                                        short* __restrict__ wb) {
    int i = blockIdx.x * 256 + threadIdx.x;
    int o = i >> 9;
    int p = i & 511;
    int g = p >> 4;
    float z = (float)qz[(size_t)g * OUT_F + o];
    float s = sc[(size_t)g * OUT_F + o];
    float zs = z * s;
    int w = qw[i];
    bf16x8 v;
#pragma unroll
    for (int j = 0; j < 8; ++j) {
        float q = (float)((w >> (4 * j)) & 15);
        v[j] = f2bf(q * s - zs);
    }
    ((bf16x8*)wb)[i] = v;
}

// ---------------- staging: global (pre-swizzled source) -> linear LDS ----------------
// LDS tile is [256 rows][64 bf16]; 16B chunk (row r, chunk c) holds global chunk (c ^ (r&7)).
__device__ __forceinline__ void stage_tile(const short* __restrict__ G, int row0, int kt,
                                           short* lds, int tid) {
#pragma unroll
    for (int i = 0; i < 4; ++i) {
        int CH = i * 512 + tid;                 // chunk index 0..2047
        int r = CH >> 3;
        int sc = (CH & 7) ^ (r & 7);            // inverse swizzle on the SOURCE
        const short* g = G + (size_t)(row0 + r) * IN_F + kt + sc * 8;
        __builtin_amdgcn_global_load_lds((const AS1 void*)g,
                                         (AS3 void*)(lds + CH * 8), 16, 0, 0);
    }
}

// ---------------- 256x256 4-phase GEMM (T1+T2+T3+T4+T5) ----------------
__global__ __launch_bounds__(512, 2) void gemm256_kernel(const short* __restrict__ A,
                                                         const short* __restrict__ B,
                                                         float* __restrict__ C) {
    __shared__ short As[2][BM * BK];            // 2 x 32 KiB
    __shared__ short Bs[2][BN * BK];            // 2 x 32 KiB   (total 128 KiB)

    const int nbn = OUT_F / BN;                 // 43
    const int nwg = (TOKENS / BM) * nbn;        // 688 = 8*86
    const int cpx = nwg >> 3;
    int bid = blockIdx.x;
    int swz = (bid & 7) * cpx + (bid >> 3);     // XCD-contiguous (bijective: 688%8==0)
    int bm = swz / nbn, bn = swz % nbn;
    const int row0 = bm * BM, col0 = bn * BN;

    const int tid = threadIdx.x;
    const int lane = tid & 63;
    const int wid = tid >> 6;                   // 8 waves: 2M x 4N
    const int wm = wid >> 2, wn = wid & 3;
    const int l15 = lane & 15, lhi = lane >> 4, l7 = lane & 7;
    // swizzled in-row byte chunks for the two K-halves (in shorts)
    const int cs0 = ((lhi ^ l7) & 7) * 8;
    const int cs1 = (((4 + lhi) ^ l7) & 7) * 8;

    f32x4 acc[8][4] = {};

    // prologue: stage K-tiles 0 and 1
    stage_tile(A, row0, 0, &As[0][0], tid);
    stage_tile(B, col0, 0, &Bs[0][0], tid);
    stage_tile(A, row0, BK, &As[1][0], tid);
    stage_tile(B, col0, BK, &Bs[1][0], tid);
    asm volatile("s_waitcnt vmcnt(8)" ::: "memory");   // tile 0 landed; tile 1 in flight
    __builtin_amdgcn_s_barrier();

    for (int t = 0; t < NKT; ++t) {
        const int cur = t & 1;
        const short* At = &As[cur][0];
        const short* Bt = &Bs[cur][0];
        bf16x8 af[8][2], bfv[4][2];

        // ---- phase 0: read A rows 0-3, B cols 0-1; MFMA m0-3 x n0-1 ----
#pragma unroll
        for (int m = 0; m < 4; ++m) {
            int r = (wm * 128 + m * 16 + l15) * BK;
            af[m][0] = *(const bf16x8*)(At + r + cs0);
            af[m][1] = *(const bf16x8*)(At + r + cs1);
        }
#pragma unroll
        for (int n = 0; n < 2; ++n) {
            int r = (wn * 64 + n * 16 + l15) * BK;
            bfv[n][0] = *(const bf16x8*)(Bt + r + cs0);
            bfv[n][1] = *(const bf16x8*)(Bt + r + cs1);
        }
        __builtin_amdgcn_s_barrier();
        __builtin_amdgcn_s_setprio(1);
#pragma unroll
        for (int m = 0; m < 4; ++m)
#pragma unroll
            for (int n = 0; n < 2; ++n)
#pragma unroll
                for (int ks = 0; ks < 2; ++ks)
                    acc[m][n] = __builtin_amdgcn_mfma_f32_16x16x32_bf16(af[m][ks], bfv[n][ks],
                                                                        acc[m][n], 0, 0, 0);
        __builtin_amdgcn_s_setprio(0);
        __builtin_amdgcn_s_barrier();

        // ---- phase 1: read A rows 4-7, B cols 2-3; MFMA m0-3 x n2-3 ----
#pragma unroll
        for (int m = 4; m < 8; ++m) {
            int r = (wm * 128 + m * 16 + l15) * BK;
            af[m][0] = *(const bf16x8*)(At + r + cs0);
            af[m][1] = *(const bf16x8*)(At + r + cs1);
        }
#pragma unroll
        for (int n = 2; n < 4; ++n) {
            int r = (wn * 64 + n * 16 + l15) * BK;
            bfv[n][0] = *(const bf16x8*)(Bt + r + cs0);
            bfv[n][1] = *(const bf16x8*)(Bt + r + cs1);
        }
        __builtin_amdgcn_s_barrier();
        __builtin_amdgcn_s_setprio(1);
#pragma unroll
        for (int m = 0; m < 4; ++m)
#pragma unroll
            for (int n = 2; n < 4; ++n)
#pragma unroll
                for (int ks = 0; ks < 2; ++ks)
                    acc[m][n] = __builtin_amdgcn_mfma_f32_16x16x32_bf16(af[m][ks], bfv[n][ks],
                                                                        acc[m][n], 0, 0, 0);
        __builtin_amdgcn_s_setprio(0);
        // fence: ALL ds_reads of buf[cur] complete before any wave passes this barrier,
        // making the phase-2 prefetch overwrite of buf[cur] race-free.
        asm volatile("s_waitcnt lgkmcnt(0)" ::: "memory");
        __builtin_amdgcn_sched_barrier(0);
        __builtin_amdgcn_s_barrier();

        // ---- phase 2: issue prefetch of tile t+2 into buf[cur]; MFMA m4-7 x n0-1 ----
        if (t < NKT - 2) {
            stage_tile(A, row0, (t + 2) * BK, &As[cur][0], tid);
            stage_tile(B, col0, (t + 2) * BK, &Bs[cur][0], tid);
        }
        __builtin_amdgcn_s_barrier();
        __builtin_amdgcn_s_setprio(1);
#pragma unroll
        for (int m = 4; m < 8; ++m)
#pragma unroll
            for (int n = 0; n < 2; ++n)
#pragma unroll
                for (int ks = 0; ks < 2; ++ks)
                    acc[m][n] = __builtin_amdgcn_mfma_f32_16x16x32_bf16(af[m][ks], bfv[n][ks],
                                                                        acc[m][n], 0, 0, 0);
        __builtin_amdgcn_s_setprio(0);
        __builtin_amdgcn_s_barrier();

        // ---- phase 3: MFMA m4-7 x n2-3; counted vmcnt; barrier ----
        __builtin_amdgcn_s_setprio(1);
#pragma unroll
        for (int m = 4; m < 8; ++m)
#pragma unroll
            for (int n = 2; n < 4; ++n)
#pragma unroll
                for (int ks = 0; ks < 2; ++ks)
                    acc[m][n] = __builtin_amdgcn_mfma_f32_16x16x32_bf16(af[m][ks], bfv[n][ks],
                                                                        acc[m][n], 0, 0, 0);
        __builtin_amdgcn_s_setprio(0);
        if (t < NKT - 2) {
            asm volatile("s_waitcnt vmcnt(8)" ::: "memory");   // t+1 landed; t+2 in flight
        } else if (t == NKT - 2) {
            asm volatile("s_waitcnt vmcnt(0)" ::: "memory");   // last tile landed
        }
        __builtin_amdgcn_s_barrier();
    }

    // ---- epilogue: C write ----
#pragma unroll
    for (int m = 0; m < 8; ++m)
#pragma unroll
        for (int n = 0; n < 4; ++n) {
            int r = row0 + wm * 128 + m * 16 + (lhi << 2);
            int c = col0 + wn * 64 + n * 16 + l15;
#pragma unroll
            for (int j = 0; j < 4; ++j)
                C[(size_t)(r + j) * OUT_F + c] = acc[m][n][j];
        }
}

// ---------------- fallback: fused dequant GEMM (128-tile, known-good) ----------------
__device__ __forceinline__ void mfma_tile128(const short* As, const short* Bs,
                                             f32x4 acc[4][4], int lane, int wm, int wn) {
#pragma unroll
    for (int kk = 0; kk < 64; kk += 32) {
        const int kb = kk + (lane >> 4) * 8;
        bf16x8 af[4], bfr[4];
#pragma unroll
        for (int m = 0; m < 4; ++m) {
            int r = wm * 64 + m * 16 + (lane & 15);
            af[m] = *(const bf16x8*)(As + r * 64 + kb);
        }
#pragma unroll
        for (int n = 0; n < 4; ++n) {
            int c = wn * 64 + n * 16 + (lane & 15);
            bfr[n] = *(const bf16x8*)(Bs + c * 64 + kb);
        }
#pragma unroll
        for (int m = 0; m < 4; ++m)
#pragma unroll
            for (int n = 0; n < 4; ++n)
                acc[m][n] = __builtin_amdgcn_mfma_f32_16x16x32_bf16(af[m], bfr[n],
                                                                    acc[m][n], 0, 0, 0);
    }
}

__global__ __launch_bounds__(256) void gemm_fused_kernel(const float* __restrict__ x,
                                                         const int* __restrict__ qw,
                                                         const int* __restrict__ qz,
                                                         const float* __restrict__ sc,
                                                         float* __restrict__ C) {
    const int nbn = OUT_F / 128;
    const int nwg = (TOKENS / 128) * nbn;
    const int cpx = nwg >> 3;
    int bid = blockIdx.x;
    int swzb = (bid & 7) * cpx + (bid >> 3);
    int bm = swzb / nbn, bn = swzb % nbn;
    const int row0 = bm * 128, col0 = bn * 128;

    __shared__ short As[128 * 64];
    __shared__ short Bs[128 * 64];

    const int tid = threadIdx.x;
    const int lane = tid & 63;
    const int wid = tid >> 6;
    const int wm = wid >> 1, wn = wid & 1;

    f32x4 acc[4][4] = {};

    for (int kt = 0; kt < IN_F; kt += 64) {
#pragma unroll
        for (int i = 0; i < 4; ++i) {
            int idx = i * 256 + tid;
            int r = idx >> 3, kc = (idx & 7) * 8;
            const float4* src = (const float4*)(x + (size_t)(row0 + r) * IN_F + kt + kc);
            float4 a = src[0], b = src[1];
            bf16x8 v;
            v[0] = f2bf(a.x); v[1] = f2bf(a.y); v[2] = f2bf(a.z); v[3] = f2bf(a.w);
            v[4] = f2bf(b.x); v[5] = f2bf(b.y); v[6] = f2bf(b.z); v[7] = f2bf(b.w);
            *(bf16x8*)(As + r * 64 + kc) = v;
        }
        {
            int ol = tid >> 1;
            int kc = (tid & 1) * 32;
            const int4* src = (const int4*)(qw + (size_t)(col0 + ol) * PACKS + ((kt + kc) >> 3));
            int4 w4 = *src;
            int g = kt >> 7;
            float z = (float)qz[(size_t)g * OUT_F + col0 + ol];
            float s = sc[(size_t)g * OUT_F + col0 + ol];
            float zs = z * s;
            const int* wp = (const int*)&w4;
#pragma unroll
            for (int c2 = 0; c2 < 4; ++c2) {
                int w32 = wp[c2];
                bf16x8 v;
#pragma unroll
                for (int j = 0; j < 8; ++j)
                    v[j] = f2bf((float)((w32 >> (4 * j)) & 15) * s - zs);
                *(bf16x8*)(Bs + ol * 64 + kc + c2 * 8) = v;
            }
        }
        __syncthreads();
        mfma_tile128(As, Bs, acc, lane, wm, wn);
        __syncthreads();
    }
#pragma unroll
    for (int m = 0; m < 4; ++m)
#pragma unroll
        for (int n = 0; n < 4; ++n) {
            int r = row0 + wm * 64 + m * 16 + ((lane >> 4) << 2);
            int c = col0 + wn * 64 + n * 16 + (lane & 15);
#pragma unroll
            for (int j = 0; j < 4; ++j)
                C[(size_t)(r + j) * OUT_F + c] = acc[m][n][j];
        }
}

extern "C" void kernel_launch(void* const* d_in, const int* in_sizes, int n_in,
                              void* d_out, int out_size, void* d_ws, size_t ws_size,
                              hipStream_t stream) {
    const float* x = (const float*)d_in[0];
    const int* qw = (const int*)d_in[1];
    const int* qz = (const int*)d_in[2];
    const float* sc = (const float*)d_in[3];
    float* out = (float*)d_out;

    const size_t xb_elems = (size_t)TOKENS * IN_F;
    const size_t wb_elems = (size_t)OUT_F * IN_F;
    const size_t need = (xb_elems + wb_elems) * sizeof(short);

    if (ws_size >= need) {
        short* xb = (short*)d_ws;
        short* wb = xb + xb_elems;
        cvt_x_kernel<<<(TOKENS * IN_F / 8) / 256, 256, 0, stream>>>(x, xb);
        dequant_w_kernel<<<(OUT_F * PACKS) / 256, 256, 0, stream>>>(qw, qz, sc, wb);
        const int ngemm = (TOKENS / BM) * (OUT_F / BN);   // 688
        gemm256_kernel<<<ngemm, 512, 0, stream>>>(xb, wb, out);
    } else {
        const int ngemm = (TOKENS / 128) * (OUT_F / 128);
        gemm_fused_kernel<<<ngemm, 256, 0, stream>>>(x, qw, qz, sc, out);
    }
}

// Round 5
// 398.418 us; speedup vs baseline: 1.2432x; 1.0668x over previous
//
#include <hip/hip_runtime.h>
#include <hip/hip_bf16.h>
#include <stdint.h>

#define TOKENS 4096
#define IN_F   4096
#define OUT_F  11008
#define PACKS  512          // IN_F/8
#define GCOUNT 32           // IN_F/128

#define BM 256
#define BN 256
#define BK 64
#define NKT (IN_F / BK)     // 64

typedef __attribute__((ext_vector_type(8))) short bf16x8;
typedef __attribute__((ext_vector_type(4))) float f32x4;

#define AS1 __attribute__((address_space(1)))
#define AS3 __attribute__((address_space(3)))

static __device__ __forceinline__ short f2bf(float f) {
    union { __hip_bfloat16 h; short s; } u;
    u.h = __float2bfloat16(f);
    return u.s;
}

// ---------------- pre-pass: x fp32 -> bf16 ----------------
__global__ __launch_bounds__(256) void cvt_x_kernel(const float* __restrict__ x,
                                                    short* __restrict__ xb) {
    int i = blockIdx.x * 256 + threadIdx.x;
    const float4* s = (const float4*)x + (size_t)i * 2;
    float4 a = s[0], b = s[1];
    bf16x8 v;
    v[0] = f2bf(a.x); v[1] = f2bf(a.y); v[2] = f2bf(a.z); v[3] = f2bf(a.w);
    v[4] = f2bf(b.x); v[5] = f2bf(b.y); v[6] = f2bf(b.z); v[7] = f2bf(b.w);
    ((bf16x8*)xb)[i] = v;
}

// ---------------- pre-pass: dequant W -> bf16 [OUT_F][IN_F] ----------------
__global__ __launch_bounds__(256) void dequant_w_kernel(const int* __restrict__ qw,
                                                        const int* __restrict__ qz,
                                                        const float* __restrict__ sc,
                                                        short* __restrict__ wb) {
    int i = blockIdx.x * 256 + threadIdx.x;
    int o = i >> 9;
    int p = i & 511;
    int g = p >> 4;
    float z = (float)qz[(size_t)g * OUT_F + o];
    float s = sc[(size_t)g * OUT_F + o];
    float zs = z * s;
    int w = qw[i];
    bf16x8 v;
#pragma unroll
    for (int j = 0; j < 8; ++j) {
        float q = (float)((w >> (4 * j)) & 15);
        v[j] = f2bf(q * s - zs);
    }
    ((bf16x8*)wb)[i] = v;
}

// ---------------- staging: global (pre-swizzled source) -> linear LDS ----------------
// LDS tile [256 rows][64 bf16]; 16B chunk (row r, chunk c) holds global chunk (c ^ (r&7)).
__device__ __forceinline__ void stage_tile(const short* __restrict__ G, int row0, int kt,
                                           short* lds, int tid) {
#pragma unroll
    for (int i = 0; i < 4; ++i) {
        int CH = i * 512 + tid;                 // chunk index 0..2047
        int r = CH >> 3;
        int sc = (CH & 7) ^ (r & 7);            // inverse swizzle on the SOURCE
        const short* g = G + (size_t)(row0 + r) * IN_F + kt + sc * 8;
        __builtin_amdgcn_global_load_lds((const AS1 void*)g,
                                         (AS3 void*)(lds + CH * 8), 16, 0, 0);
    }
}

// ---------------- 256x256 pipelined 4-phase GEMM ----------------
// Clusters: K0=(m0-3,n0-1) K1=(m0-3,n2-3) K2=(m4-7,n0-1) K3=(m4-7,n2-3)
// Reads one phase ahead of use; K2/K3 of tile t run in ph0/ph1 of tile t+1.
__global__ __launch_bounds__(512, 2) void gemm256_kernel(const short* __restrict__ A,
                                                         const short* __restrict__ B,
                                                         float* __restrict__ C) {
    __shared__ short As[2][BM * BK];            // 2 x 32 KiB
    __shared__ short Bs[2][BN * BK];            // 2 x 32 KiB (128 KiB total)

    const int nbn = OUT_F / BN;                 // 43
    const int nwg = (TOKENS / BM) * nbn;        // 688 = 8*86
    const int cpx = nwg >> 3;
    int bid = blockIdx.x;
    int swz = (bid & 7) * cpx + (bid >> 3);     // XCD-contiguous (bijective)
    int bm = swz / nbn, bn = swz % nbn;
    const int row0 = bm * BM, col0 = bn * BN;

    const int tid = threadIdx.x;
    const int lane = tid & 63;
    const int wid = tid >> 6;                   // 8 waves: 2M x 4N
    const int wm = wid >> 2, wn = wid & 3;
    const int l15 = lane & 15, lhi = lane >> 4, l7 = lane & 7;
    const int cs0 = ((lhi ^ l7) & 7) * 8;       // swizzled chunk for ks0
    const int cs1 = (((4 + lhi) ^ l7) & 7) * 8; // swizzled chunk for ks1

    f32x4 acc[8][4] = {};
    bf16x8 afA[4][2], afB[4][2], bfA[2][2], bfB[2][2];

    // prologue: stage A0,B0,A1 (B1 staged in ph0 of t=0)
    stage_tile(A, row0, 0, &As[0][0], tid);
    stage_tile(B, col0, 0, &Bs[0][0], tid);
    stage_tile(A, row0, BK, &As[1][0], tid);
    asm volatile("s_waitcnt vmcnt(4)" ::: "memory");   // A0,B0 landed; A1 in flight
    __builtin_amdgcn_s_barrier();

    for (int t = 0; t < NKT; ++t) {
        const int cur = t & 1;
        const short* At = &As[cur][0];
        const short* Bt = &Bs[cur][0];

        // ---- phase 0: read afA(t); stage B(t+1); MFMA K2(t-1) ----
#pragma unroll
        for (int m = 0; m < 4; ++m) {
            int r = (wm * 128 + m * 16 + l15) * BK;
            afA[m][0] = *(const bf16x8*)(At + r + cs0);
            afA[m][1] = *(const bf16x8*)(At + r + cs1);
        }
        if (t < NKT - 1)
            stage_tile(B, col0, (t + 1) * BK, &Bs[cur ^ 1][0], tid);
        __builtin_amdgcn_sched_barrier(0);
        if (t > 0) {
            __builtin_amdgcn_s_setprio(1);
#pragma unroll
            for (int m = 0; m < 4; ++m)
#pragma unroll
                for (int n = 0; n < 2; ++n)
#pragma unroll
                    for (int ks = 0; ks < 2; ++ks)
                        acc[4 + m][n] = __builtin_amdgcn_mfma_f32_16x16x32_bf16(
                            afB[m][ks], bfA[n][ks], acc[4 + m][n], 0, 0, 0);
            __builtin_amdgcn_s_setprio(0);
        }
        __builtin_amdgcn_s_barrier();

        // ---- phase 1: read bfA(t); MFMA K3(t-1) ----
#pragma unroll
        for (int n = 0; n < 2; ++n) {
            int r = (wn * 64 + n * 16 + l15) * BK;
            bfA[n][0] = *(const bf16x8*)(Bt + r + cs0);
            bfA[n][1] = *(const bf16x8*)(Bt + r + cs1);
        }
        __builtin_amdgcn_sched_barrier(0);
        if (t > 0) {
            __builtin_amdgcn_s_setprio(1);
#pragma unroll
            for (int m = 0; m < 4; ++m)
#pragma unroll
                for (int n = 0; n < 2; ++n)
#pragma unroll
                    for (int ks = 0; ks < 2; ++ks)
                        acc[4 + m][2 + n] = __builtin_amdgcn_mfma_f32_16x16x32_bf16(
                            afB[m][ks], bfB[n][ks], acc[4 + m][2 + n], 0, 0, 0);
            __builtin_amdgcn_s_setprio(0);
        }
        __builtin_amdgcn_s_barrier();

        // ---- phase 2: read afB(t), bfB(t); MFMA K0(t); drain buf[cur] reads ----
#pragma unroll
        for (int m = 0; m < 4; ++m) {
            int r = (wm * 128 + (4 + m) * 16 + l15) * BK;
            afB[m][0] = *(const bf16x8*)(At + r + cs0);
            afB[m][1] = *(const bf16x8*)(At + r + cs1);
        }
#pragma unroll
        for (int n = 0; n < 2; ++n) {
            int r = (wn * 64 + (2 + n) * 16 + l15) * BK;
            bfB[n][0] = *(const bf16x8*)(Bt + r + cs0);
            bfB[n][1] = *(const bf16x8*)(Bt + r + cs1);
        }
        __builtin_amdgcn_sched_barrier(0);
        __builtin_amdgcn_s_setprio(1);
#pragma unroll
        for (int m = 0; m < 4; ++m)
#pragma unroll
            for (int n = 0; n < 2; ++n)
#pragma unroll
                for (int ks = 0; ks < 2; ++ks)
                    acc[m][n] = __builtin_amdgcn_mfma_f32_16x16x32_bf16(
                        afA[m][ks], bfA[n][ks], acc[m][n], 0, 0, 0);
        __builtin_amdgcn_s_setprio(0);
        // all reads of buf[cur] (this tile) complete before any wave stages over it
        asm volatile("s_waitcnt lgkmcnt(0)" ::: "memory");
        __builtin_amdgcn_sched_barrier(0);
        __builtin_amdgcn_s_barrier();

        // ---- phase 3: stage A(t+2) into buf[cur]; MFMA K1(t); counted vmcnt ----
        if (t < NKT - 2)
            stage_tile(A, row0, (t + 2) * BK, &As[cur][0], tid);
        __builtin_amdgcn_sched_barrier(0);
        __builtin_amdgcn_s_setprio(1);
#pragma unroll
        for (int m = 0; m < 4; ++m)
#pragma unroll
            for (int n = 0; n < 2; ++n)
#pragma unroll
                for (int ks = 0; ks < 2; ++ks)
                    acc[m][2 + n] = __builtin_amdgcn_mfma_f32_16x16x32_bf16(
                        afA[m][ks], bfB[n][ks], acc[m][2 + n], 0, 0, 0);
        __builtin_amdgcn_s_setprio(0);
        if (t < NKT - 2) {
            asm volatile("s_waitcnt vmcnt(4)" ::: "memory");   // tile t+1 landed; A(t+2) in flight
        } else if (t == NKT - 2) {
            asm volatile("s_waitcnt vmcnt(0)" ::: "memory");   // everything landed for t=63
        }
        __builtin_amdgcn_s_barrier();
    }

    // ---- pipeline tail: K2(63), K3(63) ----
#pragma unroll
    for (int m = 0; m < 4; ++m)
#pragma unroll
        for (int n = 0; n < 2; ++n)
#pragma unroll
            for (int ks = 0; ks < 2; ++ks) {
                acc[4 + m][n] = __builtin_amdgcn_mfma_f32_16x16x32_bf16(
                    afB[m][ks], bfA[n][ks], acc[4 + m][n], 0, 0, 0);
                acc[4 + m][2 + n] = __builtin_amdgcn_mfma_f32_16x16x32_bf16(
                    afB[m][ks], bfB[n][ks], acc[4 + m][2 + n], 0, 0, 0);
            }

    // ---- epilogue: C write ----
#pragma unroll
    for (int m = 0; m < 8; ++m)
#pragma unroll
        for (int n = 0; n < 4; ++n) {
            int r = row0 + wm * 128 + m * 16 + (lhi << 2);
            int c = col0 + wn * 64 + n * 16 + l15;
#pragma unroll
            for (int j = 0; j < 4; ++j)
                C[(size_t)(r + j) * OUT_F + c] = acc[m][n][j];
        }
}

// ---------------- fallback: fused dequant GEMM (128-tile, known-good) ----------------
__device__ __forceinline__ void mfma_tile128(const short* As, const short* Bs,
                                             f32x4 acc[4][4], int lane, int wm, int wn) {
#pragma unroll
    for (int kk = 0; kk < 64; kk += 32) {
        const int kb = kk + (lane >> 4) * 8;
        bf16x8 af[4], bfr[4];
#pragma unroll
        for (int m = 0; m < 4; ++m) {
            int r = wm * 64 + m * 16 + (lane & 15);
            af[m] = *(const bf16x8*)(As + r * 64 + kb);
        }
#pragma unroll
        for (int n = 0; n < 4; ++n) {
            int c = wn * 64 + n * 16 + (lane & 15);
            bfr[n] = *(const bf16x8*)(Bs + c * 64 + kb);
        }
#pragma unroll
        for (int m = 0; m < 4; ++m)
#pragma unroll
            for (int n = 0; n < 4; ++n)
                acc[m][n] = __builtin_amdgcn_mfma_f32_16x16x32_bf16(af[m], bfr[n],
                                                                    acc[m][n], 0, 0, 0);
    }
}

__global__ __launch_bounds__(256) void gemm_fused_kernel(const float* __restrict__ x,
                                                         const int* __restrict__ qw,
                                                         const int* __restrict__ qz,
                                                         const float* __restrict__ sc,
                                                         float* __restrict__ C) {
    const int nbn = OUT_F / 128;
    const int nwg = (TOKENS / 128) * nbn;
    const int cpx = nwg >> 3;
    int bid = blockIdx.x;
    int swzb = (bid & 7) * cpx + (bid >> 3);
    int bm = swzb / nbn, bn = swzb % nbn;
    const int row0 = bm * 128, col0 = bn * 128;

    __shared__ short As[128 * 64];
    __shared__ short Bs[128 * 64];

    const int tid = threadIdx.x;
    const int lane = tid & 63;
    const int wid = tid >> 6;
    const int wm = wid >> 1, wn = wid & 1;

    f32x4 acc[4][4] = {};

    for (int kt = 0; kt < IN_F; kt += 64) {
#pragma unroll
        for (int i = 0; i < 4; ++i) {
            int idx = i * 256 + tid;
            int r = idx >> 3, kc = (idx & 7) * 8;
            const float4* src = (const float4*)(x + (size_t)(row0 + r) * IN_F + kt + kc);
            float4 a = src[0], b = src[1];
            bf16x8 v;
            v[0] = f2bf(a.x); v[1] = f2bf(a.y); v[2] = f2bf(a.z); v[3] = f2bf(a.w);
            v[4] = f2bf(b.x); v[5] = f2bf(b.y); v[6] = f2bf(b.z); v[7] = f2bf(b.w);
            *(bf16x8*)(As + r * 64 + kc) = v;
        }
        {
            int ol = tid >> 1;
            int kc = (tid & 1) * 32;
            const int4* src = (const int4*)(qw + (size_t)(col0 + ol) * PACKS + ((kt + kc) >> 3));
            int4 w4 = *src;
            int g = kt >> 7;
            float z = (float)qz[(size_t)g * OUT_F + col0 + ol];
            float s = sc[(size_t)g * OUT_F + col0 + ol];
            float zs = z * s;
            const int* wp = (const int*)&w4;
#pragma unroll
            for (int c2 = 0; c2 < 4; ++c2) {
                int w32 = wp[c2];
                bf16x8 v;
#pragma unroll
                for (int j = 0; j < 8; ++j)
                    v[j] = f2bf((float)((w32 >> (4 * j)) & 15) * s - zs);
                *(bf16x8*)(Bs + ol * 64 + kc + c2 * 8) = v;
            }
        }
        __syncthreads();
        mfma_tile128(As, Bs, acc, lane, wm, wn);
        __syncthreads();
    }
#pragma unroll
    for (int m = 0; m < 4; ++m)
#pragma unroll
        for (int n = 0; n < 4; ++n) {
            int r = row0 + wm * 64 + m * 16 + ((lane >> 4) << 2);
            int c = col0 + wn * 64 + n * 16 + (lane & 15);
#pragma unroll
            for (int j = 0; j < 4; ++j)
                C[(size_t)(r + j) * OUT_F + c] = acc[m][n][j];
        }
}

extern "C" void kernel_launch(void* const* d_in, const int* in_sizes, int n_in,
                              void* d_out, int out_size, void* d_ws, size_t ws_size,
                              hipStream_t stream) {
    const float* x = (const float*)d_in[0];
    const int* qw = (const int*)d_in[1];
    const int* qz = (const int*)d_in[2];
    const float* sc = (const float*)d_in[3];
    float* out = (float*)d_out;

    const size_t xb_elems = (size_t)TOKENS * IN_F;
    const size_t wb_elems = (size_t)OUT_F * IN_F;
    const size_t need = (xb_elems + wb_elems) * sizeof(short);

    if (ws_size >= need) {
        short* xb = (short*)d_ws;
        short* wb = xb + xb_elems;
        cvt_x_kernel<<<(TOKENS * IN_F / 8) / 256, 256, 0, stream>>>(x, xb);
        dequant_w_kernel<<<(OUT_F * PACKS) / 256, 256, 0, stream>>>(qw, qz, sc, wb);
        const int ngemm = (TOKENS / BM) * (OUT_F / BN);   // 688
        gemm256_kernel<<<ngemm, 512, 0, stream>>>(xb, wb, out);
    } else {
        const int ngemm = (TOKENS / 128) * (OUT_F / 128);
        gemm_fused_kernel<<<ngemm, 256, 0, stream>>>(x, qw, qz, sc, out);
    }
}